// Round 7
// baseline (66.393 us; speedup 1.0000x reference)
//
#include <hip/hip_runtime.h>

// ASTDecoder: batched GCN on a fixed banded graph (i<->i+1, i<->i+2), 2048
// graphs x 256 nodes. Only 9 distinct rows/graph survive 3 layers (8 boundary
// + 1 interior; tail mirrors head). History: 102 -> 92 -> 78 -> 73 -> 65.6us.
// Write floor ~41us (fill: 6.9 TB/s, plain stores). R6 analysis: fused NT
// stores imply only ~5 TB/s effective + per-block head with no scheduling
// slack. R7: split. A = R6's wave-specialized compute -> 9.4 MB row table
// (register->global, no staging). B = LDS-free pure streamer, plain f32x4
// stores (the proven 6.9 TB/s path), interior row held in registers.

#define NB   2048
#define EMB  256
#define HID  64
#define ODIM 128
#define NN   256
#define NROW 9
#define MG   4            // graphs per block (kernel A)
#define NBLK (NB / MG)

typedef float f32x4 __attribute__((ext_vector_type(4)));

__device__ __forceinline__ float dinvf(int j) {
  // deg: node0=3, node1=4, nodes 2..253=5 (mirror symmetric); only j<=9 used.
  if (j == 0) return 0.57735026918962576f;  // 1/sqrt(3)
  if (j == 1) return 0.5f;                  // 1/sqrt(4)
  return 0.44721359549995794f;              // 1/sqrt(5)
}

struct Smem {
  float e[MG][EMB];        // staged embeddings
  float red[8][MG][HID];   // init split-K partials
  float X8s[MG][4][HID];   // interior chain levels (interior waves)
  float X8b[MG][4][HID];   // boundary waves' private chain copy
  float Xb[MG][8][HID];    // boundary rows
};

// One boundary-path GCN layer (intra-wave dataflow only).
template <int L, int ND_IN>
__device__ __forceinline__ void boundary_layer(Smem& s, int g, int j,
                                               const float* __restrict__ convW,
                                               const float* __restrict__ convB) {
  const float* W  = convW + L * HID * HID;
  const float* bb = convB + L * HID;

  // interior-row chain step: g8 = X8^L @ W (col j), pre-bias/pre-relu
  float g8 = 0.f;
  #pragma unroll
  for (int k0 = 0; k0 < HID; k0 += 4) {
    const f32x4 xv = *reinterpret_cast<const f32x4*>(&s.X8b[g][L][k0]);
    g8 = fmaf(xv[0], W[(k0 + 0) * HID + j], g8);
    g8 = fmaf(xv[1], W[(k0 + 1) * HID + j], g8);
    g8 = fmaf(xv[2], W[(k0 + 2) * HID + j], g8);
    g8 = fmaf(xv[3], W[(k0 + 3) * HID + j], g8);
  }
  s.X8b[g][L + 1][j] = fmaxf(g8 + bb[j], 0.f);

  // boundary G rows (register accumulators)
  float accR[ND_IN > 0 ? ND_IN : 1];
  #pragma unroll
  for (int r = 0; r < (ND_IN > 0 ? ND_IN : 1); ++r) accR[r] = 0.f;
  if constexpr (ND_IN > 0) {
    #pragma unroll
    for (int k0 = 0; k0 < HID; k0 += 4) {
      float w[4];
      #pragma unroll
      for (int c = 0; c < 4; ++c) w[c] = W[(k0 + c) * HID + j];
      #pragma unroll
      for (int r = 0; r < ND_IN; ++r) {
        const f32x4 xv = *reinterpret_cast<const f32x4*>(&s.Xb[g][r][k0]);
        accR[r] = fmaf(xv[0], w[0], accR[r]);
        accR[r] = fmaf(xv[1], w[1], accR[r]);
        accR[r] = fmaf(xv[2], w[2], accR[r]);
        accR[r] = fmaf(xv[3], w[3], accR[r]);
      }
    }
  }

  // banded mix
  constexpr int NDN = (ND_IN + 2 < 4) ? 4 : (ND_IN + 2);
  float xnew[NDN];
  #pragma unroll
  for (int i = 0; i < NDN; ++i) {
    const float di = dinvf(i);
    float acc = 0.f;
    #pragma unroll
    for (int jj = (i >= 2 ? i - 2 : 0); jj <= i + 2; ++jj) {
      const float v = (jj < ND_IN) ? accR[jj] : g8;
      acc = fmaf(di * dinvf(jj), v, acc);
    }
    xnew[i] = fmaxf(acc + bb[j], 0.f);
  }
  #pragma unroll
  for (int i = 0; i < NDN; ++i) s.Xb[g][i][j] = xnew[i];
}

// ---------------- Kernel A: distinct-row table ----------------
__global__ __launch_bounds__(512) void compute_rows(
    const float* __restrict__ emb,
    const float* __restrict__ W_emb,
    const float* __restrict__ b_emb,
    const float* __restrict__ convW,
    const float* __restrict__ convB,
    const float* __restrict__ Wout,
    const float* __restrict__ bout,
    float* __restrict__ Ot)   // [NB][NROW][ODIM]
{
  const int tid   = threadIdx.x;
  const int lane  = tid & 63;
  const int wid   = tid >> 6;
  const int gbase = blockIdx.x * MG;

  __shared__ __align__(16) Smem s;

  if (tid < MG * EMB / 4) {
    const int g = tid >> 6, q = tid & 63;
    *reinterpret_cast<f32x4*>(&s.e[g][q * 4]) =
        *reinterpret_cast<const f32x4*>(&emb[(size_t)(gbase + g) * EMB + q * 4]);
  }
  __syncthreads();

  // init split-K: wid = k-eighth, lane = col j, all MG graphs
  {
    const int k0 = wid * 32, j = lane;
    float a[MG] = {0.f, 0.f, 0.f, 0.f};
    #pragma unroll
    for (int kk = 0; kk < 32; kk += 4) {
      float w[4];
      #pragma unroll
      for (int c = 0; c < 4; ++c) w[c] = W_emb[(k0 + kk + c) * HID + j];
      #pragma unroll
      for (int g = 0; g < MG; ++g) {
        const f32x4 ev = *reinterpret_cast<const f32x4*>(&s.e[g][k0 + kk]);
        a[g] = fmaf(ev[0], w[0], a[g]);
        a[g] = fmaf(ev[1], w[1], a[g]);
        a[g] = fmaf(ev[2], w[2], a[g]);
        a[g] = fmaf(ev[3], w[3], a[g]);
      }
    }
    #pragma unroll
    for (int g = 0; g < MG; ++g) s.red[wid][g][lane] = a[g];
  }
  __syncthreads();   // last barrier

  const int g = wid & 3, j = lane;
  float* OtG = Ot + (size_t)(gbase + g) * (NROW * ODIM);

  {
    float v = b_emb[j];
    #pragma unroll
    for (int kq = 0; kq < 8; ++kq) v += s.red[kq][g][j];
    if (wid < 4) s.X8s[g][0][j] = v;
    else         s.X8b[g][0][j] = v;
  }

  if (wid < 4) {
    // interior path: chain + O-row 8
    #pragma unroll
    for (int l = 0; l < 3; ++l) {
      const float* W = convW + l * HID * HID;
      float acc = 0.f;
      #pragma unroll
      for (int k0 = 0; k0 < HID; k0 += 4) {
        const f32x4 xv = *reinterpret_cast<const f32x4*>(&s.X8s[g][l][k0]);
        acc = fmaf(xv[0], W[(k0 + 0) * HID + j], acc);
        acc = fmaf(xv[1], W[(k0 + 1) * HID + j], acc);
        acc = fmaf(xv[2], W[(k0 + 2) * HID + j], acc);
        acc = fmaf(xv[3], W[(k0 + 3) * HID + j], acc);
      }
      s.X8s[g][l + 1][j] = fmaxf(acc + convB[l * HID + j], 0.f);
    }
    float a0 = bout[j], a1 = bout[j + 64];
    #pragma unroll
    for (int k0 = 0; k0 < HID; k0 += 4) {
      const f32x4 xv = *reinterpret_cast<const f32x4*>(&s.X8s[g][3][k0]);
      #pragma unroll
      for (int c = 0; c < 4; ++c) {
        a0 = fmaf(xv[c], Wout[(k0 + c) * ODIM + j], a0);
        a1 = fmaf(xv[c], Wout[(k0 + c) * ODIM + j + 64], a1);
      }
    }
    OtG[8 * ODIM + j]      = a0;
    OtG[8 * ODIM + 64 + j] = a1;
  } else {
    // boundary path
    boundary_layer<0, 0>(s, g, j, convW, convB);
    boundary_layer<1, 4>(s, g, j, convW, convB);
    boundary_layer<2, 6>(s, g, j, convW, convB);

    float aa[8], ab[8];
    #pragma unroll
    for (int r = 0; r < 8; ++r) { aa[r] = bout[j]; ab[r] = bout[j + 64]; }
    #pragma unroll
    for (int k0 = 0; k0 < HID; k0 += 4) {
      float w0[4], w1[4];
      #pragma unroll
      for (int c = 0; c < 4; ++c) {
        w0[c] = Wout[(k0 + c) * ODIM + j];
        w1[c] = Wout[(k0 + c) * ODIM + j + 64];
      }
      #pragma unroll
      for (int r = 0; r < 8; ++r) {
        const f32x4 xv = *reinterpret_cast<const f32x4*>(&s.Xb[g][r][k0]);
        #pragma unroll
        for (int c = 0; c < 4; ++c) {
          aa[r] = fmaf(xv[c], w0[c], aa[r]);
          ab[r] = fmaf(xv[c], w1[c], ab[r]);
        }
      }
    }
    #pragma unroll
    for (int r = 0; r < 8; ++r) {
      OtG[r * ODIM + j]      = aa[r];
      OtG[r * ODIM + 64 + j] = ab[r];
    }
  }
}

// ---------------- Kernel B: LDS-free broadcast streamer ----------------
// One block per graph. 256 threads = 8 nodes x 32 f32x4 slots. Interior row
// lives in a register; 30 pure-store iterations cover nodes 8..247. Plain
// stores (write-back path, full lines) — the fill kernel's 6.9 TB/s path.
__global__ __launch_bounds__(256) void bcast(
    const float* __restrict__ Ot,
    float* __restrict__ out)
{
  const int g    = blockIdx.x;
  const int tid  = threadIdx.x;
  const int q    = tid & 31;   // f32x4 slot within a 512 B node row
  const int nsub = tid >> 5;   // 0..7

  const float* OtG = Ot + (size_t)g * (NROW * ODIM);
  f32x4* outg = reinterpret_cast<f32x4*>(out + (size_t)g * NN * ODIM);

  const f32x4 vint = *reinterpret_cast<const f32x4*>(&OtG[8 * ODIM + q * 4]);

  // boundary nodes: 0..7 (row = node) and 248..255 (row = 255 - node)
  const f32x4 v0 = *reinterpret_cast<const f32x4*>(&OtG[nsub * ODIM + q * 4]);
  outg[nsub * 32 + q] = v0;
  const f32x4 v1 = *reinterpret_cast<const f32x4*>(&OtG[(7 - nsub) * ODIM + q * 4]);
  outg[(248 + nsub) * 32 + q] = v1;

  // interior nodes 8..247: 30 iterations x 8 nodes, 4 KB per block-iteration
  #pragma unroll 6
  for (int it = 1; it <= 30; ++it)
    outg[(it * 8 + nsub) * 32 + q] = vint;
}

extern "C" void kernel_launch(void* const* d_in, const int* in_sizes, int n_in,
                              void* d_out, int out_size, void* d_ws, size_t ws_size,
                              hipStream_t stream) {
  const float* emb   = (const float*)d_in[0];
  const float* W_emb = (const float*)d_in[1];
  const float* b_emb = (const float*)d_in[2];
  const float* convW = (const float*)d_in[3];
  const float* convB = (const float*)d_in[4];
  const float* Wout  = (const float*)d_in[5];
  const float* bout  = (const float*)d_in[6];
  float* out = (float*)d_out;
  float* Ot  = (float*)d_ws;   // NB*NROW*ODIM f32 = 9.4 MB

  hipLaunchKernelGGL(compute_rows, dim3(NBLK), dim3(512), 0, stream,
                     emb, W_emb, b_emb, convW, convB, Wout, bout, Ot);
  hipLaunchKernelGGL(bcast, dim3(NB), dim3(256), 0, stream, Ot, out);
}